// Round 14
// baseline (735.908 us; speedup 1.0000x reference)
//
#include <hip/hip_runtime.h>

// ---------- types ----------
// NOTE: gfx builtins (cvt_pkrtz, fdot2) use __fp16 ext-vectors, NOT _Float16.
typedef __fp16 f16x2 __attribute__((ext_vector_type(2)));
typedef unsigned u32x2 __attribute__((ext_vector_type(2)));

// ---------- lane/scalar helpers ----------
static __device__ __forceinline__ float rdlane(float v, int l) {
  return __uint_as_float(__builtin_amdgcn_readlane(__float_as_uint(v), (unsigned)l));
}
static __device__ __forceinline__ unsigned rdlane_u(unsigned v, int l) {
  return __builtin_amdgcn_readlane(v, (unsigned)l);
}

template <int CTRL>
static __device__ __forceinline__ float qperm(float v) {
  return __uint_as_float(__builtin_amdgcn_update_dpp(
      0u, __float_as_uint(v), CTRL, 0xF, 0xF, true));
}

// v_permlane32_swap, vdst=vsrc=v: vsrc result at lanes<32 holds v[lane+32].
// (Bit-identical refcheck R12->R13.)
static __device__ __forceinline__ float xswap_hi(float v) {
#if __has_builtin(__builtin_amdgcn_permlane32_swap)
  u32x2 r = __builtin_amdgcn_permlane32_swap(
      __float_as_uint(v), __float_as_uint(v), false, false);
  return __uint_as_float(r.y);
#else
  float a = v, b;
  asm("v_mov_b32 %0, %1\n\t"
      "s_nop 1\n\t"
      "v_permlane32_swap_b32 %1, %0"
      : "=&v"(b), "+v"(a));
  return b;
#endif
}

static __device__ __forceinline__ float exp2a(float x) {
  float r;
  asm("v_exp_f32 %0, %1" : "=v"(r) : "v"(x));
  return r;
}
static __device__ __forceinline__ float rcpa(float x) {
  return __builtin_amdgcn_rcpf(x);
}

// f32 += f16x2 . f16x2
static __device__ __forceinline__ float dot2f(f16x2 a, unsigned bu, float c) {
#if __has_builtin(__builtin_amdgcn_fdot2)
  return __builtin_amdgcn_fdot2(a, __builtin_bit_cast(f16x2, bu), c, false);
#else
  float r = c;
  f16x2 b = __builtin_bit_cast(f16x2, bu);
  asm("v_dot2_f32_f16 %0, %1, %2, %0" : "+v"(r) : "v"(a), "v"(b));
  return r;
#endif
}

#define QP_XOR1 0xB1  // [1,0,3,2]
#define QP_XOR2 0x4E  // [2,3,0,1]
#define QP_XOR3 0x1B  // [3,2,1,0]
#define QP_BC3  0xFF  // broadcast quad lane 3 (o)

// ---- LDS pair-buffer geometry: 2 chunk buffers, 64 step-slots each,
// slot stride 65 words (260 B). Stride 65 ≡ 1 (mod 32) =>
//   A write  (word = s*65 + lane): banks = lane mod 32      -> 2/bank, free
//   B read   (word = lane*65+4m):  banks = (lane+4m) mod 32 -> 2/bank, free
#define SLOT_W 65
#define BUF_W  (64 * SLOT_W)

// 2-wave block per sequence. Wave A (tid<64): L1 producer — computes the
// h1 recurrence, writes f16 pair-packs to LDS one chunk ahead. Wave B
// (tid>=64): L2 consumer — bulk-loads a chunk of pairs into VGPRs, runs
// the L2 recurrence, stores the output chunk. lane = 4*j + gt both waves.
//
// Scale folding (R3), dot2 matvecs (R8), VALU pair-build (R9/R12/R13),
// lane-1 cs2 trick (R12) all carried over unchanged.
__global__ __launch_bounds__(128, 1) void vdd_lstm_kernel(
    const float* __restrict__ x,      // [B,T]
    const float* __restrict__ Wih1,   // [64]
    const float* __restrict__ Whh1,   // [64,16]
    const float* __restrict__ b1,     // [64]
    const float* __restrict__ Wih2,   // [4,16]
    const float* __restrict__ Whh2,   // [4]
    const float* __restrict__ b2,     // [4]
    const float* __restrict__ mask1,  // [B,16]
    const float* __restrict__ mask2,  // [B]
    float* __restrict__ out,          // [B,T]
    int T) {
  __shared__ unsigned lds_u[2 * BUF_W];  // 33280 B

  const int b = blockIdx.x;
  const int tid = threadIdx.x;   // 128 threads = 2 waves
  const bool isA = tid < 64;
  const int lane = tid & 63;
  const int j = lane >> 2;
  const int gt = lane & 3;
  const int row = gt * 16 + j;

  const float LOG2E = 1.4426950408889634f;
  const bool isg = (gt == 2);
  const float sc = isg ? (-2.f * LOG2E) : (-LOG2E);
  const float aA = isg ? (-4.f * LOG2E) : 1.f;
  const float aC = isg ? (2.f * LOG2E) : 0.f;
  const bool isl1 = (lane == 1);

  const float* xb = x + (size_t)b * T;
  float* ob = out + (size_t)b * T;
  const int NCH = T >> 6;
  const int tmax = T - 1;

  if (isA) {
    // ================= WAVE A: layer-1 producer =================
    f16x2 wh1[8];
#pragma unroll
    for (int m = 0; m < 8; ++m) {
      wh1[m].x = (__fp16)(Whh1[row * 16 + m] * sc);
      wh1[m].y = (__fp16)(Whh1[row * 16 + m + 8] * sc);
    }
    const float wih1 = Wih1[row] * sc;
    const float bb1  = b1[row] * sc;

    float h, cs;
    // L1 step 0 (h_prev = 0), base-lane form
    {
      float pre = __fmaf_rn(wih1, xb[0], bb1);
      float a1 = __fmaf_rn(aA, rcpa(1.f + exp2a(pre)), aC);
      float g1 = qperm<QP_XOR2>(a1);
      float o1 = qperm<QP_XOR3>(a1);
      cs = a1 * g1;
      float th = __fmaf_rn(2.f, rcpa(1.f + exp2a(cs)), -1.f);
      h = o1 * th;  // h1(0) at base lanes
    }

    // x window for chunk 0: w[lane] = x[1 + lane] (clamped)
    int idx0 = 1 + lane; idx0 = idx0 > tmax ? tmax : idx0;
    float w = xb[idx0];

    for (int c = 0; c <= NCH; ++c) {
      if (c < NCH) {
        int idxn = (c + 1) * 64 + 1 + lane;   // window for chunk c+1
        idxn = idxn > tmax ? tmax : idxn;
        float wn = xb[idxn];
        unsigned* buf = lds_u + (c & 1) * BUF_W;

#pragma unroll 16
        for (int s = 0; s < 64; ++s) {
          // pair-build of h(t), t = c*64+s; publish to LDS slot s
          float hhi = xswap_hi(h);      // lanes<32: h[lane+32]
          f16x2 tp = __builtin_bit_cast(
              f16x2, __builtin_amdgcn_cvt_pkrtz(h, hhi));
          unsigned tpu = __builtin_bit_cast(unsigned, tp);
          buf[s * SLOT_W + lane] = tpu;   // full-wave, conflict-free

          unsigned sp[8];
#pragma unroll
          for (int m = 0; m < 8; ++m) sp[m] = rdlane_u(tpu, 4 * m);

          float sx = rdlane(w, s);  // x(t+1)

          // L1 dots -> pre(t+1)
          float accA2 = __fmaf_rn(wih1, sx, bb1);
          float accB2 = dot2f(wh1[1], sp[1], 0.f);
          accA2 = dot2f(wh1[0], sp[0], accA2);
          accB2 = dot2f(wh1[3], sp[3], accB2);
          accA2 = dot2f(wh1[2], sp[2], accA2);
          accB2 = dot2f(wh1[5], sp[5], accB2);
          accA2 = dot2f(wh1[4], sp[4], accA2);
          accB2 = dot2f(wh1[7], sp[7], accB2);
          accA2 = dot2f(wh1[6], sp[6], accA2);
          float pre = accA2 + accB2;

          // sigmoid + gates (base-lane form) + cell + tanh
          float a1 = __fmaf_rn(aA, rcpa(1.f + exp2a(pre)), aC);
          float f1 = qperm<QP_XOR1>(a1);
          float g1 = qperm<QP_XOR2>(a1);
          float o1 = qperm<QP_XOR3>(a1);
          cs = __fmaf_rn(f1, cs, a1 * g1);
          float th = __fmaf_rn(2.f, rcpa(1.f + exp2a(cs)), -1.f);
          h = o1 * th;  // h(t+1) at base lanes
        }
        w = wn;
      }
      __syncthreads();
    }
  } else {
    // ================= WAVE B: layer-2 consumer =================
    f16x2 wh2[8];
#pragma unroll
    for (int m = 0; m < 8; ++m) {
      wh2[m].x = (__fp16)(Wih2[gt * 16 + m] * mask1[b * 16 + m] * sc);
      wh2[m].y = (__fp16)(Wih2[gt * 16 + m + 8] * mask1[b * 16 + m + 8] * sc);
    }
    const float whh2 = Whh2[gt] * sc;
    const float bb2  = b2[gt] * sc;
    const float m2   = mask2[b];

    float cs2p = 0.f;   // cs2 (valid at lane 1)
    float h2b = 0.f;    // h2(t-1), all lanes

    for (int c = 0; c <= NCH; ++c) {
      if (c > 0) {
        const int cc = c - 1;
        const unsigned* buf = lds_u + (cc & 1) * BUF_W;
        // bulk-load chunk cc's pairs: P[m] lane s = pair m of step s
        unsigned P[8];
#pragma unroll
        for (int m = 0; m < 8; ++m) P[m] = buf[lane * SLOT_W + 4 * m];

        float och = 0.f;
#pragma unroll 16
        for (int s = 0; s < 64; ++s) {
          unsigned sp[8];
#pragma unroll
          for (int m = 0; m < 8; ++m) sp[m] = rdlane_u(P[m], s);

          // L2 dots -> pre2(t) (t = cc*64+s)
          float accC = dot2f(wh2[0], sp[0], bb2);
          float accD = dot2f(wh2[1], sp[1], 0.f);
          accC = dot2f(wh2[2], sp[2], accC);
          accD = dot2f(wh2[3], sp[3], accD);
          accC = dot2f(wh2[4], sp[4], accC);
          accD = dot2f(wh2[5], sp[5], accD);
          accC = dot2f(wh2[6], sp[6], accC);
          accD = dot2f(wh2[7], sp[7], accD);
          float pre2 = __fmaf_rn(whh2, h2b, accC + accD);

          // sigmoid + lane-1 cs2 update (R12-proven) + tanh + output
          float a2 = __fmaf_rn(aA, rcpa(1.f + exp2a(pre2)), aC);
          float i2l = qperm<QP_XOR1>(a2);
          float g2l = qperm<QP_XOR3>(a2);
          cs2p = __fmaf_rn(a2, cs2p, i2l * g2l);  // cs2(t) at lane 1
          float o2b = qperm<QP_BC3>(a2);          // o2(t), all lanes
          float thv = __fmaf_rn(2.f, rcpa(1.f + exp2a(cs2p)), -1.f);
          float th2 = rdlane(thv, 1);             // tanh(cs2(t))
          h2b = o2b * th2;                        // h2(t)
          float ov = h2b * m2;
          och = (lane == s) ? ov : och;
        }
        ob[(cc << 6) + lane] = och;  // coalesced chunk store
      }
      __syncthreads();
    }
  }
}

extern "C" void kernel_launch(void* const* d_in, const int* in_sizes, int n_in,
                              void* d_out, int out_size, void* d_ws, size_t ws_size,
                              hipStream_t stream) {
  const float* x     = (const float*)d_in[0];
  const float* Wih1  = (const float*)d_in[1];
  const float* Whh1  = (const float*)d_in[2];
  const float* b1    = (const float*)d_in[3];
  const float* Wih2  = (const float*)d_in[4];
  const float* Whh2  = (const float*)d_in[5];
  const float* b2    = (const float*)d_in[6];
  const float* mask1 = (const float*)d_in[7];
  const float* mask2 = (const float*)d_in[8];
  float* out = (float*)d_out;

  const int B = in_sizes[8];      // mask2 has B elements
  const int T = in_sizes[0] / B;  // x is [B,T,1]

  vdd_lstm_kernel<<<dim3(B), dim3(128), 0, stream>>>(
      x, Wih1, Whh1, b1, Wih2, Whh2, b2, mask1, mask2, out, T);
}

// Round 15
// 541.295 us; speedup vs baseline: 1.3595x; 1.3595x over previous
//
#include <hip/hip_runtime.h>

// ---------- types ----------
// NOTE: gfx builtins (cvt_pkrtz, fdot2) use __fp16 ext-vectors, NOT _Float16.
typedef __fp16 f16x2 __attribute__((ext_vector_type(2)));
typedef unsigned u32x2 __attribute__((ext_vector_type(2)));

// ---------- lane/scalar helpers ----------
static __device__ __forceinline__ float rdlane(float v, int l) {
  return __uint_as_float(__builtin_amdgcn_readlane(__float_as_uint(v), (unsigned)l));
}
static __device__ __forceinline__ unsigned rdlane_u(unsigned v, int l) {
  return __builtin_amdgcn_readlane(v, (unsigned)l);
}

template <int CTRL>
static __device__ __forceinline__ float qperm(float v) {
  // DPP quad_perm: pure VALU cross-lane within each 4-lane quad.
  return __uint_as_float(__builtin_amdgcn_update_dpp(
      0u, __float_as_uint(v), CTRL, 0xF, 0xF, true));
}

// v_permlane32_swap with vdst=vsrc=v. Hardware-validated mapping (R12/R13
// refchecks, bit-identical absmax): the VSRC result has, at lanes<32,
// v[lane+32].
static __device__ __forceinline__ float xswap_hi(float v) {
#if __has_builtin(__builtin_amdgcn_permlane32_swap)
  u32x2 r = __builtin_amdgcn_permlane32_swap(
      __float_as_uint(v), __float_as_uint(v), false, false);
  return __uint_as_float(r.y);  // vsrc result: lanes<32 hold v[lane+32]
#else
  float a = v, b;
  asm("v_mov_b32 %0, %1\n\t"
      "s_nop 1\n\t"
      "v_permlane32_swap_b32 %1, %0"
      : "=&v"(b), "+v"(a));
  return b;
#endif
}

static __device__ __forceinline__ float exp2a(float x) {
  float r;
  asm("v_exp_f32 %0, %1" : "=v"(r) : "v"(x));
  return r;
}
static __device__ __forceinline__ float rcpa(float x) {
  return __builtin_amdgcn_rcpf(x);
}

// f32 += f16x2 . f16x2  (v_dot2_f32_f16: f16 multiply, f32 accumulate)
static __device__ __forceinline__ float dot2f(f16x2 a, unsigned bu, float c) {
#if __has_builtin(__builtin_amdgcn_fdot2)
  return __builtin_amdgcn_fdot2(a, __builtin_bit_cast(f16x2, bu), c, false);
#else
  float r = c;
  f16x2 b = __builtin_bit_cast(f16x2, bu);
  asm("v_dot2_f32_f16 %0, %1, %2, %0" : "+v"(r) : "v"(a), "v"(b));
  return r;
#endif
}

#define QP_XOR1 0xB1  // [1,0,3,2]
#define QP_XOR2 0x4E  // [2,3,0,1]
#define QP_XOR3 0x1B  // [3,2,1,0]
#define QP_BC3  0xFF  // broadcast quad lane 3 (o)

// lane = 4*j + gt (j: hidden unit 0..15, gt: gate i,f,g,o; torch row gt*16+j).
//
// Scale folding (R3): sigmoid rows *= -log2e, g rows *= -2log2e; g-gate
// output pre-scaled so cs = -2log2e*c; tanh(c) = 2*rcp(1+exp2(cs)) - 1.
// dot2 matvecs (R8) on a shared f16 pair-broadcast; VALU pair-build (R9).
// R11 schedule (6 trans/body, decoupled merged tanh, one-body-lagged L2).
// R12: direct-partner swap; lane-1-only cs2 update.
// R13: builtin permlane swap; unroll 16.  (R14's 2-wave split REVERTED:
// producer-consumer across waves regressed 539->736 µs — barrier drain
// serializes the chains and duplicates the pair-broadcast.)
__global__ __launch_bounds__(64, 1) void vdd_lstm_kernel(
    const float* __restrict__ x,      // [B,T]
    const float* __restrict__ Wih1,   // [64]
    const float* __restrict__ Whh1,   // [64,16]
    const float* __restrict__ b1,     // [64]
    const float* __restrict__ Wih2,   // [4,16]
    const float* __restrict__ Whh2,   // [4]
    const float* __restrict__ b2,     // [4]
    const float* __restrict__ mask1,  // [B,16]
    const float* __restrict__ mask2,  // [B]
    float* __restrict__ out,          // [B,T]
    int T) {
  const int b = blockIdx.x;
  const int lane = threadIdx.x;  // 64 threads
  const int j = lane >> 2;
  const int gt = lane & 3;
  const int row = gt * 16 + j;

  const float LOG2E = 1.4426950408889634f;
  const bool isg = (gt == 2);
  const float sc = isg ? (-2.f * LOG2E) : (-LOG2E);
  const float aA = isg ? (-4.f * LOG2E) : 1.f;
  const float aC = isg ? (2.f * LOG2E) : 0.f;
  const bool isl1 = (lane == 1);  // loop-invariant lane mask

  // L1 weights as 8 f16 pairs {w[m], w[m+8]} (pre-scaled).
  f16x2 wh1[8];
#pragma unroll
  for (int m = 0; m < 8; ++m) {
    wh1[m].x = (__fp16)(Whh1[row * 16 + m] * sc);
    wh1[m].y = (__fp16)(Whh1[row * 16 + m + 8] * sc);
  }
  // L2 weights (mask1 + scale folded) as 8 f16 pairs {k=m, k=m+8}.
  f16x2 wh2[8];
#pragma unroll
  for (int m = 0; m < 8; ++m) {
    wh2[m].x = (__fp16)(Wih2[gt * 16 + m] * mask1[b * 16 + m] * sc);
    wh2[m].y = (__fp16)(Wih2[gt * 16 + m + 8] * mask1[b * 16 + m + 8] * sc);
  }
  const float wih1 = Wih1[row] * sc;
  const float bb1  = b1[row] * sc;
  const float whh2 = Whh2[gt] * sc;
  const float bb2  = b2[gt] * sc;
  const float m2   = mask2[b];

  const float* xb = x + (size_t)b * T;
  float* ob = out + (size_t)b * T;

  float h, cs;                  // L1 state (valid on quad-BASE lanes)
  float cs2p = 0.f;             // cs2(t-1)  (valid at lane 1)
  float o2p = 0.f;              // o2(t-1)   (all lanes)
  float och = 0.f;              // output chunk register

  const int NCH = T >> 6;
  const int tmax = T - 1;

  // ---- L1 step 0 (h_prev = 0), base-lane form ----
  {
    float pre = __fmaf_rn(wih1, xb[0], bb1);
    float a1 = __fmaf_rn(aA, rcpa(1.f + exp2a(pre)), aC);
    float g1 = qperm<QP_XOR2>(a1);
    float o1 = qperm<QP_XOR3>(a1);
    cs = a1 * g1;  // i (at base) * g
    float th = __fmaf_rn(2.f, rcpa(1.f + exp2a(cs)), -1.f);
    h = o1 * th;   // h1(0), valid at base lanes
  }

  // One pipeline body for step t. sx = x(t+1). If doSel, selects
  // ov(t-1) into och slot `slot`.
  auto body = [&](float sx, bool doSel, int slot) {
    // pair-build of h(t): partner straight out of the permlane swap.
    float hhi = xswap_hi(h);           // lanes<32: h[lane+32]
    f16x2 tp = __builtin_bit_cast(
        f16x2, __builtin_amdgcn_cvt_pkrtz(h, hhi));
    unsigned tpu = __builtin_bit_cast(unsigned, tp);
    unsigned sp[8];
#pragma unroll
    for (int m = 0; m < 8; ++m) sp[m] = rdlane_u(tpu, 4 * m);  // lanes 0..28

    // L1 dots -> pre(t+1)
    float accA = __fmaf_rn(wih1, sx, bb1);
    float accB = dot2f(wh1[1], sp[1], 0.f);
    accA = dot2f(wh1[0], sp[0], accA);
    accB = dot2f(wh1[3], sp[3], accB);
    accA = dot2f(wh1[2], sp[2], accA);
    accB = dot2f(wh1[5], sp[5], accB);
    accA = dot2f(wh1[4], sp[4], accA);
    accB = dot2f(wh1[7], sp[7], accB);
    accA = dot2f(wh1[6], sp[6], accA);
    float pre = accA + accB;

    // L2 dots -> d2(t) = Wih2m . h(t) + bb2
    float accC = dot2f(wh2[0], sp[0], bb2);
    float accD = dot2f(wh2[1], sp[1], 0.f);
    accC = dot2f(wh2[2], sp[2], accC);
    accD = dot2f(wh2[3], sp[3], accD);
    accC = dot2f(wh2[4], sp[4], accC);
    accD = dot2f(wh2[5], sp[5], accD);
    accC = dot2f(wh2[6], sp[6], accC);
    accD = dot2f(wh2[7], sp[7], accD);
    float d2 = accC + accD;

    // P1 sigmoid + L1 gates (base-lane form)
    float a1 = __fmaf_rn(aA, rcpa(1.f + exp2a(pre)), aC);
    float f1 = qperm<QP_XOR1>(a1);
    float g1 = qperm<QP_XOR2>(a1);
    float o1 = qperm<QP_XOR3>(a1);
    cs = __fmaf_rn(f1, cs, a1 * g1);   // cs(t+1), valid at base lanes

    // P3 merged tanh: base -> tanh(cs(t+1)); lane 1 -> tanh(cs2(t-1))
    float z = isl1 ? cs2p : cs;
    float thv = __fmaf_rn(2.f, rcpa(1.f + exp2a(z)), -1.f);
    float hn = o1 * thv;               // h(t+1) at base lanes
    float th2 = rdlane(thv, 1);        // tanh(cs2(t-1)), SGPR
    float h2b = o2p * th2;             // h2(t-1), uniform

    // pre2(t) -> P2 sigmoid -> L2 gates
    float pre2 = __fmaf_rn(whh2, h2b, d2);
    float a2 = __fmaf_rn(aA, rcpa(1.f + exp2a(pre2)), aC);
    // cs2 update, lane-1-only: a2@1=f, qXOR1@1=i, qXOR3@1=g
    float i2l = qperm<QP_XOR1>(a2);
    float g2l = qperm<QP_XOR3>(a2);
    cs2p = __fmaf_rn(a2, cs2p, i2l * g2l);  // cs2(t) at lane 1
    o2p = qperm<QP_BC3>(a2);                // o2(t), all lanes

    // output for step t-1
    float ov = h2b * m2;
    if (doSel) och = (lane == slot) ? ov : och;
    h = hn;
  };

  // x window for chunk 0: w[lane] = x[2 + lane] (clamped)
  int idx0 = 2 + lane;
  idx0 = idx0 > tmax ? tmax : idx0;
  float w = xb[idx0];

  // ---- prologue body t=0 (produces ov(-1) = 0; no select) ----
  body(xb[1], false, 0);

  for (int ch = 0; ch < NCH; ++ch) {
    // prefetch next chunk's window: x[(ch+1)*64 + 2 + lane] (clamped)
    int idxn = (ch + 1) * 64 + 2 + lane;
    idxn = idxn > tmax ? tmax : idxn;
    float wn = xb[idxn];

#pragma unroll 16
    for (int s2 = 0; s2 < 64; ++s2) {
      // body t = ch*64 + 1 + s2; needs x(t+1) = x[ch*64 + 2 + s2] = w[s2]
      float sx = rdlane(w, s2);
      body(sx, true, s2);  // selects ov(t-1) into slot (t-1)&63 = s2
    }

    ob[(ch << 6) + lane] = och;  // chunk ch fully resident -> coalesced store
    w = wn;
  }
}

extern "C" void kernel_launch(void* const* d_in, const int* in_sizes, int n_in,
                              void* d_out, int out_size, void* d_ws, size_t ws_size,
                              hipStream_t stream) {
  const float* x     = (const float*)d_in[0];
  const float* Wih1  = (const float*)d_in[1];
  const float* Whh1  = (const float*)d_in[2];
  const float* b1    = (const float*)d_in[3];
  const float* Wih2  = (const float*)d_in[4];
  const float* Whh2  = (const float*)d_in[5];
  const float* b2    = (const float*)d_in[6];
  const float* mask1 = (const float*)d_in[7];
  const float* mask2 = (const float*)d_in[8];
  float* out = (float*)d_out;

  const int B = in_sizes[8];      // mask2 has B elements
  const int T = in_sizes[0] / B;  // x is [B,T,1]

  vdd_lstm_kernel<<<dim3(B), dim3(64), 0, stream>>>(
      x, Wih1, Whh1, b1, Wih2, Whh2, b2, mask1, mask2, out, T);
}